// Round 6
// baseline (218.993 us; speedup 1.0000x reference)
//
#include <hip/hip_runtime.h>
#include <stdint.h>

// Problem constants
#define B 8
#define N 2048
#define D 16
#define KNN 32
#define DM 256
#define CAP 256  // candidate cap; approx-tau yields ~44 candidates (z~30 margin)

// ---------------------------------------------------------------------------
// K1: fused prep. Identical arithmetic to the proven version; xcrd stored
// TRANSPOSED [B][D][N] so knn_main's fill loads are lane-contiguous.
// Block 64: W transpose + pe bias/loss (verbatim).
// ---------------------------------------------------------------------------
__global__ __launch_bounds__(256) void knn_prep(
    const float* __restrict__ x, const float* __restrict__ features,
    const float* __restrict__ Wc, const float* __restrict__ Wf,
    const float* __restrict__ pec, const float* __restrict__ pef,
    float* __restrict__ xcrdT, float* __restrict__ sq,
    float* __restrict__ Tc, float* __restrict__ Tf,
    float* __restrict__ WcT, float* __restrict__ WfT,
    float* __restrict__ cbias, float* __restrict__ pe_loss_out)
{
    if (blockIdx.x == 64) {
        int dm = threadIdx.x;
        float cb = 0.f, al = 0.f;
#pragma unroll
        for (int p = 0; p < D; ++p)
            cb += pec[p * DM + dm] + pef[p * DM + dm];
#pragma unroll
        for (int p = 0; p < D; ++p)
            al += fabsf(pec[p * DM + dm]) + fabsf(pef[p * DM + dm]);
        cbias[dm] = cb;
#pragma unroll
        for (int k = 0; k < KNN; ++k) {
            WcT[k * DM + dm] = Wc[dm * KNN + k];
            WfT[k * DM + dm] = Wf[dm * KNN + k];
        }
        __shared__ float redf[256];
        redf[dm] = al; __syncthreads();
        for (int st = 128; st > 0; st >>= 1) {
            if (dm < st) redf[dm] += redf[dm + st];
            __syncthreads();
        }
        if (dm == 0) pe_loss_out[0] = redf[0];
        return;
    }

    int tid = threadIdx.x;
    int b = blockIdx.x >> 3;

    // ---- own-batch stats: 8 rows per thread, fp64 accumulate ----
    double ls[D], lq[D];
#pragma unroll
    for (int d = 0; d < D; ++d) { ls[d] = 0.0; lq[d] = 0.0; }
    for (int r = 0; r < 8; ++r) {
        const float* row = x + ((size_t)b * N + r * 256 + tid) * D;
#pragma unroll
        for (int d = 0; d < D; d += 4) {
            float4 v = *(const float4*)(row + d);
            double x0 = v.x, x1 = v.y, x2 = v.z, x3 = v.w;
            ls[d]   += x0; lq[d]   += x0 * x0;
            ls[d+1] += x1; lq[d+1] += x1 * x1;
            ls[d+2] += x2; lq[d+2] += x2 * x2;
            ls[d+3] += x3; lq[d+3] += x3 * x3;
        }
    }
#pragma unroll
    for (int d = 0; d < D; ++d) {
        double s = ls[d], q = lq[d];
#pragma unroll
        for (int st = 32; st >= 1; st >>= 1) {
            s += __shfl_xor(s, st, 64);
            q += __shfl_xor(q, st, 64);
        }
        ls[d] = s; lq[d] = q;
    }
    __shared__ double sred[4][2 * D];
    __shared__ float smean[32], sscale[32];
    int wave = tid >> 6, lane = tid & 63;
    if (lane == 0) {
#pragma unroll
        for (int d = 0; d < D; ++d) {
            sred[wave][d]     = ls[d];
            sred[wave][D + d] = lq[d];
        }
    }
    __syncthreads();
    if (tid < D) {
        int d = tid;
        double S = sred[0][d] + sred[1][d] + sred[2][d] + sred[3][d];
        double Q = sred[0][D+d] + sred[1][D+d] + sred[2][D+d] + sred[3][D+d];
        double mean = S / (double)N;
        double var  = (Q - S * S / (double)N) / (double)(N - 1);
        if (var < 0.0) var = 0.0;
        float stdv = (float)sqrt(var);
        float scl  = 1.0f / (stdv + 1e-5f);
        float scl0 = 1.0f / (0.0f + 1e-5f);
        bool mask = features[b * D + d] > 0.1f;
        smean [d]      = mask ? 0.0f : (float)mean;
        sscale[d]      = mask ? scl0 : scl;
        smean [16 + d] = mask ? (float)mean : 0.0f;
        sscale[16 + d] = mask ? scl : scl0;
    }
    __syncthreads();

    // ---- per-point processing (identical arithmetic; transposed store) ----
    int t = blockIdx.x * 256 + tid;
    int nn = t & (N - 1);
    float tc = 0.f, tf = 0.f, s = 0.f;
    float row[D];
#pragma unroll
    for (int d = 0; d < D; ++d) {
        float xv = x[(size_t)t * D + d];
        bool mask = features[b * D + d] > 0.1f;
        float xc = mask ? 0.f : xv;
        float xf = mask ? xv : 0.f;
        row[d] = xc;
        s += xc * xc;                            // sequential, mirrors ref sq
        float vc = (xc - smean[d])      * sscale[d];
        vc = fminf(10.f, fmaxf(-10.f, vc));
        float vf = (xf - smean[16 + d]) * sscale[16 + d];
        vf = fminf(10.f, fmaxf(-10.f, vf));
        tc += vc; tf += vf;
    }
#pragma unroll
    for (int d = 0; d < D; ++d)                  // coalesced per-d across wave
        xcrdT[((size_t)b * D + d) * N + nn] = row[d];
    sq[t] = s; Tc[t] = tc; Tf[t] = tf;
}

// ---------------------------------------------------------------------------
// K2: round-0 structure (one 64-thread block per query).  ROUND-6 CHANGE:
// fill vectorized to float4 along N -- lane owns neighbors
// m = j*256 + lane*4 + q (q=0..3, j=0..7): per j, 16 dwordx4 xcrdT loads +
// 1 dwordx4 sq load feed 4 dot accumulators.  Fill VMEM 544 -> 136
// instructions; per-neighbor arithmetic (sequential-d dot, d2, sqrt) is
// bit-identical, so dist values match the exact kernel.
//
// tau = 32nd-smallest of the 64 per-lane minima: valid upper bound on the
// exact 32nd order statistic for ANY 64-way partition of the 2048 dists
// (each of the 32 lanes with min <= tau contributes >= 1 element <= tau).
// Candidate superset -> downstream exact (dist,m)-key ranking -> output
// bit-identical.  Collect insertion order is irrelevant for T <= CAP
// (ranking sorts globally-unique keys); all-tie degenerate case collects
// the complete m in [0,256) block first, which contains the true top-32.
// ---------------------------------------------------------------------------
__global__ __launch_bounds__(64, 2) void knn_main(
    const float* __restrict__ xcrdT, const float* __restrict__ sq,
    const float* __restrict__ Tc, const float* __restrict__ Tf,
    const float* __restrict__ WcT, const float* __restrict__ WfT,
    const float* __restrict__ cbias, float* __restrict__ out)
{
    __shared__ unsigned long long collect[CAP];
    __shared__ int sortedm[KNN];

    const int lane = threadIdx.x;
    const int qid  = blockIdx.x;                 // 0..16383
    const int b = qid >> 11;
    const int n = qid & (N - 1);

    const float* xbT = xcrdT + (size_t)b * D * N;
    const float* sqb = sq + b * N;

    // query row (uniform scalar loads from the transposed layout)
    float qx[D];
#pragma unroll
    for (int d = 0; d < D; ++d)
        qx[d] = xbT[(size_t)d * N + n];
    const float sqn = sqb[n];

    // ---- fill: float4-vectorized transposed loads; 4 neighbors per lane/j ----
    float orig[8][4];
#pragma unroll
    for (int j = 0; j < 8; ++j) {
        const int m0 = j * 256 + lane * 4;
        float d0 = 0.f, d1 = 0.f, d2a = 0.f, d3 = 0.f;
#pragma unroll
        for (int d = 0; d < D; ++d) {
            float4 v = *(const float4*)(xbT + (size_t)d * N + m0);
            d0 += qx[d] * v.x;
            d1 += qx[d] * v.y;
            d2a += qx[d] * v.z;
            d3 += qx[d] * v.w;
        }
        float4 s4 = *(const float4*)(sqb + m0);
        orig[j][0] = fabsf(sqrtf(fmaxf(sqn + s4.x - 2.0f * d0, 0.f)));
        orig[j][1] = fabsf(sqrtf(fmaxf(sqn + s4.y - 2.0f * d1, 0.f)));
        orig[j][2] = fabsf(sqrtf(fmaxf(sqn + s4.z - 2.0f * d2a, 0.f)));
        orig[j][3] = fabsf(sqrtf(fmaxf(sqn + s4.w - 2.0f * d3, 0.f)));
    }

    // ---- approx tau: 32nd-smallest of the 64 per-lane minima ----
    float red[8];
#pragma unroll
    for (int j = 0; j < 8; ++j)
        red[j] = fminf(fminf(orig[j][0], orig[j][1]),
                       fminf(orig[j][2], orig[j][3]));
#pragma unroll
    for (int st = 4; st >= 1; st >>= 1)
#pragma unroll
        for (int i = 0; i < st; ++i) red[i] = fminf(red[i], red[i + st]);
    float v = red[0];
#pragma unroll
    for (int k = 2; k <= 64; k <<= 1) {
#pragma unroll
        for (int j = k >> 1; j >= 1; j >>= 1) {
            float o = __shfl_xor(v, j, 64);
            bool lower = (lane & j) == 0;
            bool up    = (lane & k) == 0;
            v = (lower == up) ? fminf(v, o) : fmaxf(v, o);
        }
    }
    const float tau = __shfl(v, 31, 64);         // >= exact 32nd smallest

    // ---- tie-fixup: compact all dist <= tau (order irrelevant; see header) ----
    const unsigned long long lmask = (1ULL << lane) - 1ULL;
    int base = 0;
#pragma unroll
    for (int j = 0; j < 8; ++j) {
#pragma unroll
        for (int q = 0; q < 4; ++q) {
            bool f = (orig[j][q] <= tau);
            unsigned long long mk = __ballot(f);
            if (f) {
                int pos = base + (int)__popcll(mk & lmask);
                if (pos < CAP)
                    collect[pos] =
                        (((unsigned long long)__float_as_uint(orig[j][q])) << 11)
                        | (unsigned)(j * 256 + lane * 4 + q);
            }
            base += (int)__popcll(mk);
        }
    }
    int T = base < CAP ? base : CAP;             // wave-uniform, >= 32
    __syncthreads();

    if (T <= 64) {
        // ---- fast path: in-wave bitonic sort of up to 64 unique keys ----
        unsigned long long key = (lane < T) ? collect[lane] : ~0ULL;
#pragma unroll
        for (int k = 2; k <= 64; k <<= 1) {
#pragma unroll
            for (int j = k >> 1; j >= 1; j >>= 1) {
                unsigned long long o = __shfl_xor(key, j, 64);
                bool lower = (lane & j) == 0;
                bool up    = (lane & k) == 0;
                unsigned long long mn = (o < key) ? o : key;
                unsigned long long mx = (o < key) ? key : o;
                key = (lower == up) ? mn : mx;
            }
        }
        if (lane < KNN)
            sortedm[lane] = (int)(key & 2047u);
    } else {
        // ---- slow path (degenerate mass ties): exact serial ranking ----
#pragma unroll 1
        for (int slot = 0; slot < CAP / 64; ++slot) {
            int i = lane + slot * 64;
            if (i < T) {
                unsigned long long mk = collect[i];
                int rank = 0;
#pragma unroll 4
                for (int t2 = 0; t2 < T; ++t2)
                    rank += (collect[t2] < mk) ? 1 : 0;
                if (rank < KNN)
                    sortedm[rank] = (int)(mk & 2047u);
            }
        }
    }
    __syncthreads();

    // ---- matvec: ranked top-32 ----
    float acc[4] = {0.f, 0.f, 0.f, 0.f};
    const float* Tcb = Tc + b * N;
    const float* Tfb = Tf + b * N;
    const float Tcn = Tcb[n], Tfn = Tfb[n];

#pragma unroll
    for (int k = 0; k < KNN; ++k) {
        int wm = sortedm[k];
        float ak = Tcb[wm] - Tcn;
        float bk = Tfb[wm] - Tfn;
        const float* wc = WcT + k * DM + lane;
        const float* wf = WfT + k * DM + lane;
#pragma unroll
        for (int q = 0; q < 4; ++q)
            acc[q] += wc[q * 64] * ak + wf[q * 64] * bk;
    }

    size_t obase = (size_t)qid * DM + lane;
#pragma unroll
    for (int q = 0; q < 4; ++q)
        out[obase + q * 64] = acc[q] + cbias[lane + q * 64];
}

// ---------------------------------------------------------------------------
extern "C" void kernel_launch(void* const* d_in, const int* in_sizes, int n_in,
                              void* d_out, int out_size, void* d_ws, size_t ws_size,
                              hipStream_t stream)
{
    const float* x        = (const float*)d_in[0];   // (B,N,D)
    const float* features = (const float*)d_in[1];   // (B,D)
    const float* W_crd    = (const float*)d_in[2];   // (DM,K)
    const float* W_ftr    = (const float*)d_in[3];   // (DM,K)
    const float* pe_crd   = (const float*)d_in[4];   // (1,1,D,DM)
    const float* pe_ftr   = (const float*)d_in[5];   // (1,1,D,DM)
    // d_in[6] = k (constant 32), ignored

    float* out = (float*)d_out;                      // B*N*DM floats + 1 (pe_loss)

    float* xcrdT = (float*)d_ws;                     // 262144 (B*D*N, transposed)
    float* sqv   = xcrdT + (size_t)B * N * D;        // 16384
    float* Tc    = sqv  + B * N;                     // 16384
    float* Tf    = Tc   + B * N;                     // 16384
    float* cbias = Tf   + B * N;                     // 256
    float* WcT   = cbias + DM;                       // 8192
    float* WfT   = WcT + KNN * DM;                   // 8192

    knn_prep<<<65, 256, 0, stream>>>(x, features, W_crd, W_ftr, pe_crd, pe_ftr,
                                     xcrdT, sqv, Tc, Tf, WcT, WfT, cbias,
                                     out + (size_t)out_size - 1);
    knn_main<<<B * N, 64, 0, stream>>>(xcrdT, sqv, Tc, Tf,
                                       WcT, WfT, cbias, out);
}

// Round 7
// 203.052 us; speedup vs baseline: 1.0785x; 1.0785x over previous
//
#include <hip/hip_runtime.h>
#include <stdint.h>

// Problem constants
#define B 8
#define N 2048
#define D 16
#define KNN 32
#define DM 256
#define CAP 256  // candidate cap; approx-tau yields ~44 candidates (z~30 margin)

// ---------------------------------------------------------------------------
// K1: fused prep (proven). xcrd stored TRANSPOSED [B][D][N] so knn_main's
// fill loads are lane-contiguous.  Block 64: W transpose + pe bias/loss.
// ---------------------------------------------------------------------------
__global__ __launch_bounds__(256) void knn_prep(
    const float* __restrict__ x, const float* __restrict__ features,
    const float* __restrict__ Wc, const float* __restrict__ Wf,
    const float* __restrict__ pec, const float* __restrict__ pef,
    float* __restrict__ xcrdT, float* __restrict__ sq,
    float* __restrict__ Tc, float* __restrict__ Tf,
    float* __restrict__ WcT, float* __restrict__ WfT,
    float* __restrict__ cbias, float* __restrict__ pe_loss_out)
{
    if (blockIdx.x == 64) {
        int dm = threadIdx.x;
        float cb = 0.f, al = 0.f;
#pragma unroll
        for (int p = 0; p < D; ++p)
            cb += pec[p * DM + dm] + pef[p * DM + dm];
#pragma unroll
        for (int p = 0; p < D; ++p)
            al += fabsf(pec[p * DM + dm]) + fabsf(pef[p * DM + dm]);
        cbias[dm] = cb;
#pragma unroll
        for (int k = 0; k < KNN; ++k) {
            WcT[k * DM + dm] = Wc[dm * KNN + k];
            WfT[k * DM + dm] = Wf[dm * KNN + k];
        }
        __shared__ float redf[256];
        redf[dm] = al; __syncthreads();
        for (int st = 128; st > 0; st >>= 1) {
            if (dm < st) redf[dm] += redf[dm + st];
            __syncthreads();
        }
        if (dm == 0) pe_loss_out[0] = redf[0];
        return;
    }

    int tid = threadIdx.x;
    int b = blockIdx.x >> 3;

    // ---- own-batch stats: 8 rows per thread, fp64 accumulate ----
    double ls[D], lq[D];
#pragma unroll
    for (int d = 0; d < D; ++d) { ls[d] = 0.0; lq[d] = 0.0; }
    for (int r = 0; r < 8; ++r) {
        const float* row = x + ((size_t)b * N + r * 256 + tid) * D;
#pragma unroll
        for (int d = 0; d < D; d += 4) {
            float4 v = *(const float4*)(row + d);
            double x0 = v.x, x1 = v.y, x2 = v.z, x3 = v.w;
            ls[d]   += x0; lq[d]   += x0 * x0;
            ls[d+1] += x1; lq[d+1] += x1 * x1;
            ls[d+2] += x2; lq[d+2] += x2 * x2;
            ls[d+3] += x3; lq[d+3] += x3 * x3;
        }
    }
#pragma unroll
    for (int d = 0; d < D; ++d) {
        double s = ls[d], q = lq[d];
#pragma unroll
        for (int st = 32; st >= 1; st >>= 1) {
            s += __shfl_xor(s, st, 64);
            q += __shfl_xor(q, st, 64);
        }
        ls[d] = s; lq[d] = q;
    }
    __shared__ double sred[4][2 * D];
    __shared__ float smean[32], sscale[32];
    int wave = tid >> 6, lane = tid & 63;
    if (lane == 0) {
#pragma unroll
        for (int d = 0; d < D; ++d) {
            sred[wave][d]     = ls[d];
            sred[wave][D + d] = lq[d];
        }
    }
    __syncthreads();
    if (tid < D) {
        int d = tid;
        double S = sred[0][d] + sred[1][d] + sred[2][d] + sred[3][d];
        double Q = sred[0][D+d] + sred[1][D+d] + sred[2][D+d] + sred[3][D+d];
        double mean = S / (double)N;
        double var  = (Q - S * S / (double)N) / (double)(N - 1);
        if (var < 0.0) var = 0.0;
        float stdv = (float)sqrt(var);
        float scl  = 1.0f / (stdv + 1e-5f);
        float scl0 = 1.0f / (0.0f + 1e-5f);
        bool mask = features[b * D + d] > 0.1f;
        smean [d]      = mask ? 0.0f : (float)mean;
        sscale[d]      = mask ? scl0 : scl;
        smean [16 + d] = mask ? (float)mean : 0.0f;
        sscale[16 + d] = mask ? scl : scl0;
    }
    __syncthreads();

    // ---- per-point processing (identical arithmetic; transposed store) ----
    int t = blockIdx.x * 256 + tid;
    int nn = t & (N - 1);
    float tc = 0.f, tf = 0.f, s = 0.f;
    float row[D];
#pragma unroll
    for (int d = 0; d < D; ++d) {
        float xv = x[(size_t)t * D + d];
        bool mask = features[b * D + d] > 0.1f;
        float xc = mask ? 0.f : xv;
        float xf = mask ? xv : 0.f;
        row[d] = xc;
        s += xc * xc;                            // sequential, mirrors ref sq
        float vc = (xc - smean[d])      * sscale[d];
        vc = fminf(10.f, fmaxf(-10.f, vc));
        float vf = (xf - smean[16 + d]) * sscale[16 + d];
        vf = fminf(10.f, fmaxf(-10.f, vf));
        tc += vc; tf += vf;
    }
#pragma unroll
    for (int d = 0; d < D; ++d)                  // coalesced per-d across wave
        xcrdT[((size_t)b * D + d) * N + nn] = row[d];
    sq[t] = s; Tc[t] = tc; Tf[t] = tf;
}

// ---------------------------------------------------------------------------
// K2: ROUND-7 -- one wave serves TWO consecutive queries (n0 even, n1=n0+1;
// same batch since N is even).  Every fill load xbT[d*N+m] feeds both
// queries' dot accumulators and every matvec W load feeds both outputs:
// per-query VMEM halves (fill 512->256, W 256->128), waves halve, and the
// doubled FMA density hides latency better.  Fill uses the ROUND-5 PROVEN
// scalar-dword pattern (round 6's dwordx4 touched 4x the cache lines per
// instr and serialized on 48 VGPRs -- reverted).
//
// Per-query selection is the proven pipeline, duplicated: tau = 32nd-
// smallest of the 64 per-lane minima (upper bound on the exact 32nd order
// statistic for any 64-way partition; partition j*64+lane identical to
// round 5), ballot-compact of dist<=tau into per-query collect[], in-wave
// 64-key u64 bitonic rank (T<=64 fast path; serial exact ranking
// fallback).  Arithmetic per query is bit-identical to round 5.
// Spill tripwire: WRITE_SIZE must stay 16.4 MB (pure output).
// ---------------------------------------------------------------------------
__global__ __launch_bounds__(64, 2) void knn_main(
    const float* __restrict__ xcrdT, const float* __restrict__ sq,
    const float* __restrict__ Tc, const float* __restrict__ Tf,
    const float* __restrict__ WcT, const float* __restrict__ WfT,
    const float* __restrict__ cbias, float* __restrict__ out)
{
    __shared__ unsigned long long collect[2][CAP];
    __shared__ int sortedm[2][KNN];

    const int lane = threadIdx.x;
    const int qid0 = blockIdx.x * 2;             // even, 0..16382
    const int b  = qid0 >> 11;
    const int n0 = qid0 & (N - 1);               // even
    const int n1 = n0 + 1;

    const float* xbT = xcrdT + (size_t)b * D * N;
    const float* sqb = sq + b * N;

    // two query rows (n0,n1 adjacent -> float2 loads)
    float qx0[D], qx1[D];
#pragma unroll
    for (int d = 0; d < D; ++d) {
        float2 v = *(const float2*)(xbT + (size_t)d * N + n0);
        qx0[d] = v.x; qx1[d] = v.y;
    }
    const float sqn0 = sqb[n0], sqn1 = sqb[n1];

    // ---- fill: scalar-dword coalesced loads, shared by both queries ----
    float orig0[KNN], orig1[KNN];
#pragma unroll
    for (int j = 0; j < KNN; ++j) {
        int m = j * 64 + lane;
        float dot0 = 0.f, dot1 = 0.f;
#pragma unroll
        for (int d = 0; d < D; ++d) {
            float v = xbT[(size_t)d * N + m];
            dot0 += qx0[d] * v;
            dot1 += qx1[d] * v;
        }
        float sm = sqb[m];
        orig0[j] = fabsf(sqrtf(fmaxf(sqn0 + sm - 2.0f * dot0, 0.f)));
        orig1[j] = fabsf(sqrtf(fmaxf(sqn1 + sm - 2.0f * dot1, 0.f)));
    }

    // ---- approx tau per query: 32nd-smallest of the 64 per-lane minima ----
    float v0 = orig0[0], v1 = orig1[0];
#pragma unroll
    for (int j = 1; j < KNN; ++j) {
        v0 = fminf(v0, orig0[j]);
        v1 = fminf(v1, orig1[j]);
    }
#pragma unroll
    for (int k = 2; k <= 64; k <<= 1) {
#pragma unroll
        for (int j = k >> 1; j >= 1; j >>= 1) {
            float o0 = __shfl_xor(v0, j, 64);
            float o1 = __shfl_xor(v1, j, 64);
            bool lower = (lane & j) == 0;
            bool up    = (lane & k) == 0;
            v0 = (lower == up) ? fminf(v0, o0) : fmaxf(v0, o0);
            v1 = (lower == up) ? fminf(v1, o1) : fmaxf(v1, o1);
        }
    }
    const float tau0 = __shfl(v0, 31, 64);       // >= exact 32nd smallest (q0)
    const float tau1 = __shfl(v1, 31, 64);       // >= exact 32nd smallest (q1)

    // ---- tie-fixup compact, per query ----
    const unsigned long long lmask = (1ULL << lane) - 1ULL;
    int T0, T1;
    {
        int base = 0;
#pragma unroll
        for (int j = 0; j < KNN; ++j) {
            bool f = (orig0[j] <= tau0);
            unsigned long long mk = __ballot(f);
            if (f) {
                int pos = base + (int)__popcll(mk & lmask);
                if (pos < CAP)
                    collect[0][pos] =
                        (((unsigned long long)__float_as_uint(orig0[j])) << 11)
                        | (unsigned)(j * 64 + lane);
            }
            base += (int)__popcll(mk);
        }
        T0 = base < CAP ? base : CAP;
    }
    {
        int base = 0;
#pragma unroll
        for (int j = 0; j < KNN; ++j) {
            bool f = (orig1[j] <= tau1);
            unsigned long long mk = __ballot(f);
            if (f) {
                int pos = base + (int)__popcll(mk & lmask);
                if (pos < CAP)
                    collect[1][pos] =
                        (((unsigned long long)__float_as_uint(orig1[j])) << 11)
                        | (unsigned)(j * 64 + lane);
            }
            base += (int)__popcll(mk);
        }
        T1 = base < CAP ? base : CAP;
    }
    __syncthreads();

    if (T0 <= 64 && T1 <= 64) {
        // ---- fast path: two interleaved in-wave 64-key bitonic sorts ----
        unsigned long long key0 = (lane < T0) ? collect[0][lane] : ~0ULL;
        unsigned long long key1 = (lane < T1) ? collect[1][lane] : ~0ULL;
#pragma unroll
        for (int k = 2; k <= 64; k <<= 1) {
#pragma unroll
            for (int j = k >> 1; j >= 1; j >>= 1) {
                unsigned long long o0 = __shfl_xor(key0, j, 64);
                unsigned long long o1 = __shfl_xor(key1, j, 64);
                bool lower = (lane & j) == 0;
                bool up    = (lane & k) == 0;
                unsigned long long mn0 = (o0 < key0) ? o0 : key0;
                unsigned long long mx0 = (o0 < key0) ? key0 : o0;
                unsigned long long mn1 = (o1 < key1) ? o1 : key1;
                unsigned long long mx1 = (o1 < key1) ? key1 : o1;
                key0 = (lower == up) ? mn0 : mx0;
                key1 = (lower == up) ? mn1 : mx1;
            }
        }
        if (lane < KNN) {
            sortedm[0][lane] = (int)(key0 & 2047u);
            sortedm[1][lane] = (int)(key1 & 2047u);
        }
    } else {
        // ---- rare path: per-query fast/slow handling ----
#pragma unroll 1
        for (int q = 0; q < 2; ++q) {
            int T = q ? T1 : T0;
            unsigned long long* co = collect[q];
            int* so = sortedm[q];
            if (T <= 64) {
                unsigned long long key = (lane < T) ? co[lane] : ~0ULL;
#pragma unroll
                for (int k = 2; k <= 64; k <<= 1) {
#pragma unroll
                    for (int j = k >> 1; j >= 1; j >>= 1) {
                        unsigned long long o = __shfl_xor(key, j, 64);
                        bool lower = (lane & j) == 0;
                        bool up    = (lane & k) == 0;
                        unsigned long long mn = (o < key) ? o : key;
                        unsigned long long mx = (o < key) ? key : o;
                        key = (lower == up) ? mn : mx;
                    }
                }
                if (lane < KNN) so[lane] = (int)(key & 2047u);
            } else {
#pragma unroll 1
                for (int slot = 0; slot < CAP / 64; ++slot) {
                    int i = lane + slot * 64;
                    if (i < T) {
                        unsigned long long mk = co[i];
                        int rank = 0;
#pragma unroll 4
                        for (int t2 = 0; t2 < T; ++t2)
                            rank += (co[t2] < mk) ? 1 : 0;
                        if (rank < KNN) so[rank] = (int)(mk & 2047u);
                    }
                }
            }
        }
    }
    __syncthreads();

    // ---- matvec: W loads shared by both queries ----
    float acc0[4] = {0.f, 0.f, 0.f, 0.f};
    float acc1[4] = {0.f, 0.f, 0.f, 0.f};
    const float* Tcb = Tc + b * N;
    const float* Tfb = Tf + b * N;
    const float Tcn0 = Tcb[n0], Tfn0 = Tfb[n0];
    const float Tcn1 = Tcb[n1], Tfn1 = Tfb[n1];

#pragma unroll
    for (int k = 0; k < KNN; ++k) {
        int wm0 = sortedm[0][k];
        int wm1 = sortedm[1][k];
        float ak0 = Tcb[wm0] - Tcn0, bk0 = Tfb[wm0] - Tfn0;
        float ak1 = Tcb[wm1] - Tcn1, bk1 = Tfb[wm1] - Tfn1;
        const float* wc = WcT + k * DM + lane;
        const float* wf = WfT + k * DM + lane;
#pragma unroll
        for (int q = 0; q < 4; ++q) {
            float wcv = wc[q * 64];
            float wfv = wf[q * 64];
            acc0[q] += wcv * ak0 + wfv * bk0;
            acc1[q] += wcv * ak1 + wfv * bk1;
        }
    }

    size_t ob0 = (size_t)qid0 * DM + lane;
#pragma unroll
    for (int q = 0; q < 4; ++q) {
        float cb = cbias[lane + q * 64];
        out[ob0 + q * 64]      = acc0[q] + cb;
        out[ob0 + DM + q * 64] = acc1[q] + cb;
    }
}

// ---------------------------------------------------------------------------
extern "C" void kernel_launch(void* const* d_in, const int* in_sizes, int n_in,
                              void* d_out, int out_size, void* d_ws, size_t ws_size,
                              hipStream_t stream)
{
    const float* x        = (const float*)d_in[0];   // (B,N,D)
    const float* features = (const float*)d_in[1];   // (B,D)
    const float* W_crd    = (const float*)d_in[2];   // (DM,K)
    const float* W_ftr    = (const float*)d_in[3];   // (DM,K)
    const float* pe_crd   = (const float*)d_in[4];   // (1,1,D,DM)
    const float* pe_ftr   = (const float*)d_in[5];   // (1,1,D,DM)
    // d_in[6] = k (constant 32), ignored

    float* out = (float*)d_out;                      // B*N*DM floats + 1 (pe_loss)

    float* xcrdT = (float*)d_ws;                     // 262144 (B*D*N, transposed)
    float* sqv   = xcrdT + (size_t)B * N * D;        // 16384
    float* Tc    = sqv  + B * N;                     // 16384
    float* Tf    = Tc   + B * N;                     // 16384
    float* cbias = Tf   + B * N;                     // 256
    float* WcT   = cbias + DM;                       // 8192
    float* WfT   = WcT + KNN * DM;                   // 8192

    knn_prep<<<65, 256, 0, stream>>>(x, features, W_crd, W_ftr, pe_crd, pe_ftr,
                                     xcrdT, sqv, Tc, Tf, WcT, WfT, cbias,
                                     out + (size_t)out_size - 1);
    knn_main<<<(B * N) / 2, 64, 0, stream>>>(xcrdT, sqv, Tc, Tf,
                                             WcT, WfT, cbias, out);
}

// Round 8
// 177.883 us; speedup vs baseline: 1.2311x; 1.1415x over previous
//
#include <hip/hip_runtime.h>
#include <stdint.h>

// Problem constants
#define B 8
#define N 2048
#define D 16
#define KNN 32
#define DM 256
#define CAP 256  // candidate cap; approx-tau yields ~44 candidates (z~30 margin)

// ---------------------------------------------------------------------------
// K1: fused prep (proven). xcrd stored TRANSPOSED [B][D][N] so knn_main's
// fill loads are lane-contiguous.  Block 64: W transpose + pe bias/loss.
// ---------------------------------------------------------------------------
__global__ __launch_bounds__(256) void knn_prep(
    const float* __restrict__ x, const float* __restrict__ features,
    const float* __restrict__ Wc, const float* __restrict__ Wf,
    const float* __restrict__ pec, const float* __restrict__ pef,
    float* __restrict__ xcrdT, float* __restrict__ sq,
    float* __restrict__ Tc, float* __restrict__ Tf,
    float* __restrict__ WcT, float* __restrict__ WfT,
    float* __restrict__ cbias, float* __restrict__ pe_loss_out)
{
    if (blockIdx.x == 64) {
        int dm = threadIdx.x;
        float cb = 0.f, al = 0.f;
#pragma unroll
        for (int p = 0; p < D; ++p)
            cb += pec[p * DM + dm] + pef[p * DM + dm];
#pragma unroll
        for (int p = 0; p < D; ++p)
            al += fabsf(pec[p * DM + dm]) + fabsf(pef[p * DM + dm]);
        cbias[dm] = cb;
#pragma unroll
        for (int k = 0; k < KNN; ++k) {
            WcT[k * DM + dm] = Wc[dm * KNN + k];
            WfT[k * DM + dm] = Wf[dm * KNN + k];
        }
        __shared__ float redf[256];
        redf[dm] = al; __syncthreads();
        for (int st = 128; st > 0; st >>= 1) {
            if (dm < st) redf[dm] += redf[dm + st];
            __syncthreads();
        }
        if (dm == 0) pe_loss_out[0] = redf[0];
        return;
    }

    int tid = threadIdx.x;
    int b = blockIdx.x >> 3;

    // ---- own-batch stats: 8 rows per thread, fp64 accumulate ----
    double ls[D], lq[D];
#pragma unroll
    for (int d = 0; d < D; ++d) { ls[d] = 0.0; lq[d] = 0.0; }
    for (int r = 0; r < 8; ++r) {
        const float* row = x + ((size_t)b * N + r * 256 + tid) * D;
#pragma unroll
        for (int d = 0; d < D; d += 4) {
            float4 v = *(const float4*)(row + d);
            double x0 = v.x, x1 = v.y, x2 = v.z, x3 = v.w;
            ls[d]   += x0; lq[d]   += x0 * x0;
            ls[d+1] += x1; lq[d+1] += x1 * x1;
            ls[d+2] += x2; lq[d+2] += x2 * x2;
            ls[d+3] += x3; lq[d+3] += x3 * x3;
        }
    }
#pragma unroll
    for (int d = 0; d < D; ++d) {
        double s = ls[d], q = lq[d];
#pragma unroll
        for (int st = 32; st >= 1; st >>= 1) {
            s += __shfl_xor(s, st, 64);
            q += __shfl_xor(q, st, 64);
        }
        ls[d] = s; lq[d] = q;
    }
    __shared__ double sred[4][2 * D];
    __shared__ float smean[32], sscale[32];
    int wave = tid >> 6, lane = tid & 63;
    if (lane == 0) {
#pragma unroll
        for (int d = 0; d < D; ++d) {
            sred[wave][d]     = ls[d];
            sred[wave][D + d] = lq[d];
        }
    }
    __syncthreads();
    if (tid < D) {
        int d = tid;
        double S = sred[0][d] + sred[1][d] + sred[2][d] + sred[3][d];
        double Q = sred[0][D+d] + sred[1][D+d] + sred[2][D+d] + sred[3][D+d];
        double mean = S / (double)N;
        double var  = (Q - S * S / (double)N) / (double)(N - 1);
        if (var < 0.0) var = 0.0;
        float stdv = (float)sqrt(var);
        float scl  = 1.0f / (stdv + 1e-5f);
        float scl0 = 1.0f / (0.0f + 1e-5f);
        bool mask = features[b * D + d] > 0.1f;
        smean [d]      = mask ? 0.0f : (float)mean;
        sscale[d]      = mask ? scl0 : scl;
        smean [16 + d] = mask ? (float)mean : 0.0f;
        sscale[16 + d] = mask ? scl : scl0;
    }
    __syncthreads();

    // ---- per-point processing (identical arithmetic; transposed store) ----
    int t = blockIdx.x * 256 + tid;
    int nn = t & (N - 1);
    float tc = 0.f, tf = 0.f, s = 0.f;
    float row[D];
#pragma unroll
    for (int d = 0; d < D; ++d) {
        float xv = x[(size_t)t * D + d];
        bool mask = features[b * D + d] > 0.1f;
        float xc = mask ? 0.f : xv;
        float xf = mask ? xv : 0.f;
        row[d] = xc;
        s += xc * xc;                            // sequential, mirrors ref sq
        float vc = (xc - smean[d])      * sscale[d];
        vc = fminf(10.f, fmaxf(-10.f, vc));
        float vf = (xf - smean[16 + d]) * sscale[16 + d];
        vf = fminf(10.f, fmaxf(-10.f, vf));
        tc += vc; tf += vf;
    }
#pragma unroll
    for (int d = 0; d < D; ++d)                  // coalesced per-d across wave
        xcrdT[((size_t)b * D + d) * N + nn] = row[d];
    sq[t] = s; Tc[t] = tc; Tf[t] = tf;
}

// ---------------------------------------------------------------------------
// K2: ROUND-8 -- round-7 proven 2-queries-per-wave structure with two
// latency fixes (arithmetic bit-identical):
// (1) FILL software-pipelined with two NAMED register buffers (static
//     indexing; runtime-indexed arrays would spill to scratch): load j+1
//     into buf1 while computing j from buf0 -> ~17 loads in flight.
//     Deliberately raises VGPR to ~90-110 ((64,2) caps at 256).
//     Spill tripwire: WRITE_SIZE must stay 16384 KB.
// (2) MATVEC gather parallelized: lane=(q,k) loads Tc/Tf[sortedm[q][k]]
//     (128 loads in 2 lane-parallel instructions instead of 128
//     serialized wave-uniform loads), staged through LDS akbk[][].
// Selection pipeline (approx tau from 64 lane-minima -> superset compact
// -> exact 64-key u64 bitonic rank, serial fallback for T>64) unchanged
// from round 7.
// ---------------------------------------------------------------------------
#define LOADBUF(buf, sqm, j) do {                                   \
    int m_ = (j) * 64 + lane;                                       \
    _Pragma("unroll")                                               \
    for (int d_ = 0; d_ < D; ++d_)                                  \
        buf[d_] = xbT[(size_t)d_ * N + m_];                         \
    sqm = sqb[m_];                                                  \
} while (0)

#define COMPUTE(j, buf, sqm) do {                                   \
    float dot0_ = 0.f, dot1_ = 0.f;                                 \
    _Pragma("unroll")                                               \
    for (int d_ = 0; d_ < D; ++d_) {                                \
        dot0_ += qx0[d_] * buf[d_];                                 \
        dot1_ += qx1[d_] * buf[d_];                                 \
    }                                                               \
    orig0[j] = fabsf(sqrtf(fmaxf(sqn0 + sqm - 2.0f * dot0_, 0.f))); \
    orig1[j] = fabsf(sqrtf(fmaxf(sqn1 + sqm - 2.0f * dot1_, 0.f))); \
} while (0)

__global__ __launch_bounds__(64, 2) void knn_main(
    const float* __restrict__ xcrdT, const float* __restrict__ sq,
    const float* __restrict__ Tc, const float* __restrict__ Tf,
    const float* __restrict__ WcT, const float* __restrict__ WfT,
    const float* __restrict__ cbias, float* __restrict__ out)
{
    __shared__ unsigned long long collect[2][CAP];
    __shared__ int sortedm[2][KNN];
    __shared__ float akbk[2][KNN][2];            // [query][k][{a,b}]

    const int lane = threadIdx.x;
    const int qid0 = blockIdx.x * 2;             // even, 0..16382
    const int b  = qid0 >> 11;
    const int n0 = qid0 & (N - 1);               // even
    const int n1 = n0 + 1;

    const float* xbT = xcrdT + (size_t)b * D * N;
    const float* sqb = sq + b * N;

    // two query rows (n0,n1 adjacent -> float2 loads)
    float qx0[D], qx1[D];
#pragma unroll
    for (int d = 0; d < D; ++d) {
        float2 v = *(const float2*)(xbT + (size_t)d * N + n0);
        qx0[d] = v.x; qx1[d] = v.y;
    }
    const float sqn0 = sqb[n0], sqn1 = sqb[n1];

    // ---- fill: 2-deep register-double-buffered, shared by both queries ----
    float orig0[KNN], orig1[KNN];
    {
        float buf0[D], buf1[D];
        float sqm0v, sqm1v;
        LOADBUF(buf0, sqm0v, 0);
#pragma unroll
        for (int jj = 0; jj < KNN; jj += 2) {
            LOADBUF(buf1, sqm1v, jj + 1);
            COMPUTE(jj, buf0, sqm0v);
            if (jj + 2 < KNN) LOADBUF(buf0, sqm0v, jj + 2);
            COMPUTE(jj + 1, buf1, sqm1v);
        }
    }

    // ---- approx tau per query: 32nd-smallest of the 64 per-lane minima ----
    float v0 = orig0[0], v1 = orig1[0];
#pragma unroll
    for (int j = 1; j < KNN; ++j) {
        v0 = fminf(v0, orig0[j]);
        v1 = fminf(v1, orig1[j]);
    }
#pragma unroll
    for (int k = 2; k <= 64; k <<= 1) {
#pragma unroll
        for (int j = k >> 1; j >= 1; j >>= 1) {
            float o0 = __shfl_xor(v0, j, 64);
            float o1 = __shfl_xor(v1, j, 64);
            bool lower = (lane & j) == 0;
            bool up    = (lane & k) == 0;
            v0 = (lower == up) ? fminf(v0, o0) : fmaxf(v0, o0);
            v1 = (lower == up) ? fminf(v1, o1) : fmaxf(v1, o1);
        }
    }
    const float tau0 = __shfl(v0, 31, 64);       // >= exact 32nd smallest (q0)
    const float tau1 = __shfl(v1, 31, 64);       // >= exact 32nd smallest (q1)

    // ---- tie-fixup compact, per query ----
    const unsigned long long lmask = (1ULL << lane) - 1ULL;
    int T0, T1;
    {
        int base = 0;
#pragma unroll
        for (int j = 0; j < KNN; ++j) {
            bool f = (orig0[j] <= tau0);
            unsigned long long mk = __ballot(f);
            if (f) {
                int pos = base + (int)__popcll(mk & lmask);
                if (pos < CAP)
                    collect[0][pos] =
                        (((unsigned long long)__float_as_uint(orig0[j])) << 11)
                        | (unsigned)(j * 64 + lane);
            }
            base += (int)__popcll(mk);
        }
        T0 = base < CAP ? base : CAP;
    }
    {
        int base = 0;
#pragma unroll
        for (int j = 0; j < KNN; ++j) {
            bool f = (orig1[j] <= tau1);
            unsigned long long mk = __ballot(f);
            if (f) {
                int pos = base + (int)__popcll(mk & lmask);
                if (pos < CAP)
                    collect[1][pos] =
                        (((unsigned long long)__float_as_uint(orig1[j])) << 11)
                        | (unsigned)(j * 64 + lane);
            }
            base += (int)__popcll(mk);
        }
        T1 = base < CAP ? base : CAP;
    }
    __syncthreads();

    if (T0 <= 64 && T1 <= 64) {
        // ---- fast path: two interleaved in-wave 64-key bitonic sorts ----
        unsigned long long key0 = (lane < T0) ? collect[0][lane] : ~0ULL;
        unsigned long long key1 = (lane < T1) ? collect[1][lane] : ~0ULL;
#pragma unroll
        for (int k = 2; k <= 64; k <<= 1) {
#pragma unroll
            for (int j = k >> 1; j >= 1; j >>= 1) {
                unsigned long long o0 = __shfl_xor(key0, j, 64);
                unsigned long long o1 = __shfl_xor(key1, j, 64);
                bool lower = (lane & j) == 0;
                bool up    = (lane & k) == 0;
                unsigned long long mn0 = (o0 < key0) ? o0 : key0;
                unsigned long long mx0 = (o0 < key0) ? key0 : o0;
                unsigned long long mn1 = (o1 < key1) ? o1 : key1;
                unsigned long long mx1 = (o1 < key1) ? key1 : o1;
                key0 = (lower == up) ? mn0 : mx0;
                key1 = (lower == up) ? mn1 : mx1;
            }
        }
        if (lane < KNN) {
            sortedm[0][lane] = (int)(key0 & 2047u);
            sortedm[1][lane] = (int)(key1 & 2047u);
        }
    } else {
        // ---- rare path: per-query fast/slow handling ----
#pragma unroll 1
        for (int q = 0; q < 2; ++q) {
            int T = q ? T1 : T0;
            unsigned long long* co = collect[q];
            int* so = sortedm[q];
            if (T <= 64) {
                unsigned long long key = (lane < T) ? co[lane] : ~0ULL;
#pragma unroll
                for (int k = 2; k <= 64; k <<= 1) {
#pragma unroll
                    for (int j = k >> 1; j >= 1; j >>= 1) {
                        unsigned long long o = __shfl_xor(key, j, 64);
                        bool lower = (lane & j) == 0;
                        bool up    = (lane & k) == 0;
                        unsigned long long mn = (o < key) ? o : key;
                        unsigned long long mx = (o < key) ? key : o;
                        key = (lower == up) ? mn : mx;
                    }
                }
                if (lane < KNN) so[lane] = (int)(key & 2047u);
            } else {
#pragma unroll 1
                for (int slot = 0; slot < CAP / 64; ++slot) {
                    int i = lane + slot * 64;
                    if (i < T) {
                        unsigned long long mk = co[i];
                        int rank = 0;
#pragma unroll 4
                        for (int t2 = 0; t2 < T; ++t2)
                            rank += (co[t2] < mk) ? 1 : 0;
                        if (rank < KNN) so[rank] = (int)(mk & 2047u);
                    }
                }
            }
        }
    }
    __syncthreads();

    // ---- gather ak/bk lane-parallel: lane = (q,k) ----
    const float* Tcb = Tc + b * N;
    const float* Tfb = Tf + b * N;
    {
        const float Tcn0 = Tcb[n0], Tfn0 = Tfb[n0];
        const float Tcn1 = Tcb[n1], Tfn1 = Tfb[n1];
        int q = lane >> 5;                       // 0 or 1
        int k = lane & 31;
        int wm = sortedm[q][k];
        float av = Tcb[wm] - (q ? Tcn1 : Tcn0);
        float bv = Tfb[wm] - (q ? Tfn1 : Tfn0);
        akbk[q][k][0] = av;
        akbk[q][k][1] = bv;
    }
    __syncthreads();

    // ---- matvec: W loads shared by both queries; ak/bk from LDS bcast ----
    float acc0[4] = {0.f, 0.f, 0.f, 0.f};
    float acc1[4] = {0.f, 0.f, 0.f, 0.f};

#pragma unroll
    for (int k = 0; k < KNN; ++k) {
        float ak0 = akbk[0][k][0], bk0 = akbk[0][k][1];
        float ak1 = akbk[1][k][0], bk1 = akbk[1][k][1];
        const float* wc = WcT + k * DM + lane;
        const float* wf = WfT + k * DM + lane;
#pragma unroll
        for (int q = 0; q < 4; ++q) {
            float wcv = wc[q * 64];
            float wfv = wf[q * 64];
            acc0[q] += wcv * ak0 + wfv * bk0;
            acc1[q] += wcv * ak1 + wfv * bk1;
        }
    }

    size_t ob0 = (size_t)qid0 * DM + lane;
#pragma unroll
    for (int q = 0; q < 4; ++q) {
        float cb = cbias[lane + q * 64];
        out[ob0 + q * 64]      = acc0[q] + cb;
        out[ob0 + DM + q * 64] = acc1[q] + cb;
    }
}

// ---------------------------------------------------------------------------
extern "C" void kernel_launch(void* const* d_in, const int* in_sizes, int n_in,
                              void* d_out, int out_size, void* d_ws, size_t ws_size,
                              hipStream_t stream)
{
    const float* x        = (const float*)d_in[0];   // (B,N,D)
    const float* features = (const float*)d_in[1];   // (B,D)
    const float* W_crd    = (const float*)d_in[2];   // (DM,K)
    const float* W_ftr    = (const float*)d_in[3];   // (DM,K)
    const float* pe_crd   = (const float*)d_in[4];   // (1,1,D,DM)
    const float* pe_ftr   = (const float*)d_in[5];   // (1,1,D,DM)
    // d_in[6] = k (constant 32), ignored

    float* out = (float*)d_out;                      // B*N*DM floats + 1 (pe_loss)

    float* xcrdT = (float*)d_ws;                     // 262144 (B*D*N, transposed)
    float* sqv   = xcrdT + (size_t)B * N * D;        // 16384
    float* Tc    = sqv  + B * N;                     // 16384
    float* Tf    = Tc   + B * N;                     // 16384
    float* cbias = Tf   + B * N;                     // 256
    float* WcT   = cbias + DM;                       // 8192
    float* WfT   = WcT + KNN * DM;                   // 8192

    knn_prep<<<65, 256, 0, stream>>>(x, features, W_crd, W_ftr, pe_crd, pe_ftr,
                                     xcrdT, sqv, Tc, Tf, WcT, WfT, cbias,
                                     out + (size_t)out_size - 1);
    knn_main<<<(B * N) / 2, 64, 0, stream>>>(xcrdT, sqv, Tc, Tf,
                                             WcT, WfT, cbias, out);
}